// Round 4
// baseline (9621.126 us; speedup 1.0000x reference)
//
#include <hip/hip_runtime.h>
#include <hip/hip_bf16.h>

// GRU tagger. T=2048, E=H=1024, 3H=3072, TAGS=50.
// R4: weights truly register-resident (cap 256 VGPR + asm pin, no "memory" clobber
//     in poll), interleaved column slices -> conflict-free linear LDS broadcast.

#define T_SEQ 2048
#define E_DIM 1024
#define H_DIM 1024
#define N3H   3072
#define VTAGS 50
#define VOCAB 50257
#define NWG   64
#define IPW   (H_DIM / NWG)   // 16 h-rows per workgroup
#define SBLK  512             // scan block size

typedef short bf16x8 __attribute__((ext_vector_type(8)));
typedef float f32x4  __attribute__((ext_vector_type(4)));
typedef unsigned int u32x4v __attribute__((ext_vector_type(4)));

__device__ inline unsigned short f2bf_rne(float f) {
  unsigned int u = __float_as_uint(f);
  u += 0x7FFFu + ((u >> 16) & 1u);
  return (unsigned short)(u >> 16);
}

// ---------------- embedding gather + cast to bf16 ----------------
__global__ __launch_bounds__(256) void k_gather_cast(
    const int* __restrict__ sent, const float* __restrict__ emb,
    unsigned short* __restrict__ Xb) {
  const int t = blockIdx.x;
  int row = sent[t];
  row = (row < 0) ? 0 : ((row >= VOCAB) ? VOCAB - 1 : row);
  const float4* src = (const float4*)(emb + (size_t)row * E_DIM);
  float4 v = src[threadIdx.x];
  ushort4 o;
  o.x = f2bf_rne(v.x); o.y = f2bf_rne(v.y); o.z = f2bf_rne(v.z); o.w = f2bf_rne(v.w);
  ((ushort4*)(Xb + (size_t)t * E_DIM))[threadIdx.x] = o;
}

__global__ __launch_bounds__(256) void k_cast_w(
    const float* __restrict__ W, unsigned short* __restrict__ Wb) {
  const int r = blockIdx.x;
  const float4* src = (const float4*)(W + (size_t)r * E_DIM);
  float4 v = src[threadIdx.x];
  ushort4 o;
  o.x = f2bf_rne(v.x); o.y = f2bf_rne(v.y); o.z = f2bf_rne(v.z); o.w = f2bf_rne(v.w);
  ((ushort4*)(Wb + (size_t)r * E_DIM))[threadIdx.x] = o;
}

// ---------------- gi = X @ W_ih^T + b_ih  (bf16 MFMA, fp32 accum) ----------------
__global__ __launch_bounds__(256) void k_gemm_gi(
    const unsigned short* __restrict__ Xb, const unsigned short* __restrict__ Wb,
    const float* __restrict__ b_ih, float* __restrict__ gi) {
  const int tid = threadIdx.x;
  const int lane = tid & 63;
  const int wv = tid >> 6;
  const int m_base = blockIdx.y * 128 + (wv & 1) * 64;
  const int n_base = blockIdx.x * 128 + (wv >> 1) * 64;
  const int lr = lane & 15;
  const int kq = (lane >> 4) * 8;
  f32x4 acc[4][4] = {};
  for (int k0 = 0; k0 < E_DIM; k0 += 32) {
    bf16x8 a[4], b[4];
#pragma unroll
    for (int mi = 0; mi < 4; ++mi)
      a[mi] = *(const bf16x8*)(Xb + (size_t)(m_base + mi * 16 + lr) * E_DIM + k0 + kq);
#pragma unroll
    for (int ni = 0; ni < 4; ++ni)
      b[ni] = *(const bf16x8*)(Wb + (size_t)(n_base + ni * 16 + lr) * E_DIM + k0 + kq);
#pragma unroll
    for (int mi = 0; mi < 4; ++mi)
#pragma unroll
      for (int ni = 0; ni < 4; ++ni)
        acc[mi][ni] = __builtin_amdgcn_mfma_f32_16x16x32_bf16(a[mi], b[ni], acc[mi][ni], 0, 0, 0);
  }
  const int row_q = (lane >> 4) * 4;
#pragma unroll
  for (int mi = 0; mi < 4; ++mi) {
#pragma unroll
    for (int ni = 0; ni < 4; ++ni) {
      const int col  = n_base + ni * 16 + lr;
      const int row0 = m_base + mi * 16 + row_q;
      const float bv = b_ih[col];
#pragma unroll
      for (int rr = 0; rr < 4; ++rr)
        gi[(size_t)(row0 + rr) * N3H + col] = acc[mi][ni][rr] + bv;
    }
  }
}

// ---------------- persistent GRU scan ----------------
// 64 WGs x 512 threads. WG owns h-rows [wg*16, wg*16+16).
// Thread (idx=tid>>5, cg=tid&31): columns {cg*4 + 128q + k, q=0..7, k=0..3}
// -> 96 weight floats, asm-pinned in VGPRs. LDS broadcast is linear (conflict-free:
// 32 consecutive float4 reads per lane group, idx halves broadcast).
// Mailbox mb[2][1024]: {f32 h, u32 step} pairs, double-buffered by parity; wave0
// bulk-polls via sc0/sc1 dwordx4 (LLC roundtrip), no fences anywhere.
__global__ __launch_bounds__(SBLK) void k_gru_scan(
    const float* __restrict__ W_hh, const float* __restrict__ b_hh,
    const float* __restrict__ gi, float* __restrict__ hs,
    unsigned long long* mb) {
  const int wg  = blockIdx.x;
  const int tid = threadIdx.x;
  const int idx = tid >> 5;         // 0..15 : h-row within WG
  const int cg  = tid & 31;         // 0..31 : column group (interleaved)
  const int i   = wg * IPW + idx;   // global h row

  __shared__ float hsh[2][H_DIM];

  f32x4 w0[8], w1[8], w2[8];
  {
    const f32x4* p0 = (const f32x4*)(W_hh + (size_t)i * H_DIM);
    const f32x4* p1 = (const f32x4*)(W_hh + (size_t)(H_DIM + i) * H_DIM);
    const f32x4* p2 = (const f32x4*)(W_hh + (size_t)(2 * H_DIM + i) * H_DIM);
#pragma unroll
    for (int q = 0; q < 8; ++q) {
      w0[q] = p0[cg + q * 32];
      w1[q] = p1[cg + q * 32];
      w2[q] = p2[cg + q * 32];
      // pin: forces the values into VGPRs, forbids per-step rematerialization
      asm volatile("" : "+v"(w0[q]), "+v"(w1[q]), "+v"(w2[q]));
    }
  }
  const float bh0 = b_hh[i], bh1 = b_hh[H_DIM + i], bh2 = b_hh[2 * H_DIM + i];

  for (int t = 0; t < T_SEQ; ++t) {
    // gi prefetch (L2/LLC-cacheable plain loads; no fences in this kernel)
    const float gir = gi[(size_t)t * N3H + i];
    const float giz = gi[(size_t)t * N3H + H_DIM + i];
    const float gin = gi[(size_t)t * N3H + 2 * H_DIM + i];

    if (tid < 64) {
      // wave 0: poll all 1024 pairs of slot t&1 (16 pairs/lane, 8 dwordx4)
      const unsigned long long* pb = mb + (size_t)(t & 1) * H_DIM + tid * 16;
      const unsigned tt = (unsigned)t;
      u32x4v p0, p1, p2, p3, p4, p5, p6, p7;
      int iters = 0;
      while (true) {
        asm volatile(
            "global_load_dwordx4 %0, %8, off sc0 sc1\n\t"
            "global_load_dwordx4 %1, %8, off offset:16 sc0 sc1\n\t"
            "global_load_dwordx4 %2, %8, off offset:32 sc0 sc1\n\t"
            "global_load_dwordx4 %3, %8, off offset:48 sc0 sc1\n\t"
            "global_load_dwordx4 %4, %8, off offset:64 sc0 sc1\n\t"
            "global_load_dwordx4 %5, %8, off offset:80 sc0 sc1\n\t"
            "global_load_dwordx4 %6, %8, off offset:96 sc0 sc1\n\t"
            "global_load_dwordx4 %7, %8, off offset:112 sc0 sc1\n\t"
            "s_waitcnt vmcnt(0)"
            : "=v"(p0), "=v"(p1), "=v"(p2), "=v"(p3),
              "=v"(p4), "=v"(p5), "=v"(p6), "=v"(p7)
            : "v"(pb));
        bool ok = (p0[1] == tt) & (p0[3] == tt) & (p1[1] == tt) & (p1[3] == tt) &
                  (p2[1] == tt) & (p2[3] == tt) & (p3[1] == tt) & (p3[3] == tt) &
                  (p4[1] == tt) & (p4[3] == tt) & (p5[1] == tt) & (p5[3] == tt) &
                  (p6[1] == tt) & (p6[3] == tt) & (p7[1] == tt) & (p7[3] == tt);
        if (__all(ok) || ++iters > (1 << 16)) break;
      }
      // linear LDS write: 64 lanes x 4 consecutive float4s (conflict-free)
      f32x4* hb4 = (f32x4*)hsh[t & 1];
      const int q0 = tid * 4;
      hb4[q0 + 0] = f32x4{__uint_as_float(p0[0]), __uint_as_float(p0[2]),
                          __uint_as_float(p1[0]), __uint_as_float(p1[2])};
      hb4[q0 + 1] = f32x4{__uint_as_float(p2[0]), __uint_as_float(p2[2]),
                          __uint_as_float(p3[0]), __uint_as_float(p3[2])};
      hb4[q0 + 2] = f32x4{__uint_as_float(p4[0]), __uint_as_float(p4[2]),
                          __uint_as_float(p5[0]), __uint_as_float(p5[2])};
      hb4[q0 + 3] = f32x4{__uint_as_float(p6[0]), __uint_as_float(p6[2]),
                          __uint_as_float(p7[0]), __uint_as_float(p7[2])};
    }
    __syncthreads();

    const float* hb = hsh[t & 1];
    const f32x4* hb4 = (const f32x4*)hb;
    float a0 = 0.f, a1 = 0.f, a2 = 0.f;
#pragma unroll
    for (int q = 0; q < 8; ++q) {
      f32x4 hv = hb4[cg + q * 32];   // 32 consecutive float4s per lane group
      a0 = fmaf(w0[q][0], hv[0], a0); a0 = fmaf(w0[q][1], hv[1], a0);
      a0 = fmaf(w0[q][2], hv[2], a0); a0 = fmaf(w0[q][3], hv[3], a0);
      a1 = fmaf(w1[q][0], hv[0], a1); a1 = fmaf(w1[q][1], hv[1], a1);
      a1 = fmaf(w1[q][2], hv[2], a1); a1 = fmaf(w1[q][3], hv[3], a1);
      a2 = fmaf(w2[q][0], hv[0], a2); a2 = fmaf(w2[q][1], hv[1], a2);
      a2 = fmaf(w2[q][2], hv[2], a2); a2 = fmaf(w2[q][3], hv[3], a2);
    }
#pragma unroll
    for (int off = 16; off >= 1; off >>= 1) {   // reduce across 32-lane group
      a0 += __shfl_xor(a0, off, 64);
      a1 += __shfl_xor(a1, off, 64);
      a2 += __shfl_xor(a2, off, 64);
    }
    const float r = 1.f / (1.f + __expf(-(gir + a0 + bh0)));
    const float z = 1.f / (1.f + __expf(-(giz + a1 + bh1)));
    const float nx = gin + r * (a2 + bh2);
    const float e2 = __expf(-2.f * fabsf(nx));
    float n = (1.f - e2) / (1.f + e2);
    n = (nx < 0.f) ? -n : n;
    const float hold = hb[i];
    const float hnew = (1.f - z) * n + z * hold;

    if (cg == 0) {
      const unsigned long long pack =
          ((unsigned long long)(unsigned)(t + 1) << 32) |
          (unsigned long long)__float_as_uint(hnew);
      __hip_atomic_store(&mb[(size_t)((t + 1) & 1) * H_DIM + i], pack,
                         __ATOMIC_RELAXED, __HIP_MEMORY_SCOPE_AGENT);
      hs[(size_t)t * H_DIM + i] = hnew;   // consumed by k_out after kernel end
    }
    // no bottom barrier needed: mailbox+LDS double-buffered by parity; a WG can
    // only reach step t+2 (overwriting slot t&1) after ALL WGs stored step t+1,
    // which happens-after their step-t polls completed.
  }
}

// ---------------- tag head: hs @ W_out^T + b_out, log_softmax ----------------
__global__ __launch_bounds__(256) void k_out(
    const float* __restrict__ hs, const float* __restrict__ W_out,
    const float* __restrict__ b_out, float* __restrict__ out) {
  const int t = blockIdx.x;
  const int tid = threadIdx.x;
  const int wv = tid >> 6, lane = tid & 63;
  __shared__ float xs[H_DIM];
  __shared__ float tagv[64];
  ((float4*)xs)[tid] = ((const float4*)(hs + (size_t)t * H_DIM))[tid];
  __syncthreads();
  for (int g = wv; g < VTAGS; g += 4) {
    const float4* wr = (const float4*)(W_out + (size_t)g * H_DIM);
    const float4* xr = (const float4*)xs;
    float s = 0.f;
#pragma unroll
    for (int q = 0; q < 4; ++q) {
      float4 a = wr[lane * 4 + q];
      float4 b = xr[lane * 4 + q];
      s += a.x * b.x + a.y * b.y + a.z * b.z + a.w * b.w;
    }
#pragma unroll
    for (int off = 1; off < 64; off <<= 1) s += __shfl_xor(s, off, 64);
    if (lane == 0) tagv[g] = s + b_out[g];
  }
  __syncthreads();
  if (tid < 64) {
    const float v = (tid < VTAGS) ? tagv[tid] : -1e30f;
    float m = v;
#pragma unroll
    for (int off = 1; off < 64; off <<= 1) m = fmaxf(m, __shfl_xor(m, off, 64));
    float e = (tid < VTAGS) ? __expf(v - m) : 0.f;
    float se = e;
#pragma unroll
    for (int off = 1; off < 64; off <<= 1) se += __shfl_xor(se, off, 64);
    const float lse = logf(se);
    if (tid < VTAGS) out[(size_t)t * VTAGS + tid] = v - m - lse;
  }
}

extern "C" void kernel_launch(void* const* d_in, const int* in_sizes, int n_in,
                              void* d_out, int out_size, void* d_ws, size_t ws_size,
                              hipStream_t stream) {
  const int* sent    = (const int*)d_in[0];
  const float* emb   = (const float*)d_in[1];
  const float* W_ih  = (const float*)d_in[2];
  const float* W_hh  = (const float*)d_in[3];
  const float* b_ih  = (const float*)d_in[4];
  const float* b_hh  = (const float*)d_in[5];
  const float* W_out = (const float*)d_in[6];
  const float* b_out = (const float*)d_in[7];
  float* out = (float*)d_out;

  char* ws = (char*)d_ws;
  const size_t OFF_GI = 0;
  const size_t OFF_B  = (size_t)T_SEQ * N3H * 4;            // 24 MB
  const size_t OFF_XB = OFF_B;
  const size_t OFF_WB = OFF_B + (size_t)T_SEQ * E_DIM * 2;  // +4 MB
  const size_t OFF_HS = OFF_B;                              // reuse after GEMM
  const size_t OFF_MB = OFF_B + 10485760;
  const size_t NEED = OFF_MB + 2 * H_DIM * 8;
  if (ws_size < NEED) return;

  float* gi = (float*)(ws + OFF_GI);
  unsigned short* Xb = (unsigned short*)(ws + OFF_XB);
  unsigned short* Wb = (unsigned short*)(ws + OFF_WB);
  float* hs = (float*)(ws + OFF_HS);
  unsigned long long* mb = (unsigned long long*)(ws + OFF_MB);

  // zero mailbox: tags=0 == step 0, values=0 == h0  (re-run on every graph replay)
  hipMemsetAsync(mb, 0, 2 * H_DIM * 8, stream);

  k_gather_cast<<<T_SEQ, 256, 0, stream>>>(sent, emb, Xb);
  k_cast_w<<<N3H, 256, 0, stream>>>(W_ih, Wb);
  k_gemm_gi<<<dim3(N3H / 128, T_SEQ / 128), 256, 0, stream>>>(Xb, Wb, b_ih, gi);
  k_gru_scan<<<NWG, SBLK, 0, stream>>>(W_hh, b_hh, gi, hs, mb);
  k_out<<<T_SEQ, 256, 0, stream>>>(hs, W_out, b_out, out);
}

// Round 7
// 5874.585 us; speedup vs baseline: 1.6378x; 1.6378x over previous
//
#include <hip/hip_runtime.h>
#include <hip/hip_bf16.h>

// GRU tagger. T=2048, E=H=1024, 3H=3072, TAGS=50.
// R7: back to the R4-PROVEN single-domain mailbox protocol (tag-embedded
//     {h,step} pairs, two-phase poll-all, no fences). Changes vs R4:
//     (1) amdgpu_waves_per_eu(2,2) -> 96 weight floats truly VGPR-resident,
//     (2) per-thread distributed poll (1 dwordx4/thread) instead of wave0-only,
//     (3) producer stores stay __hip_atomic_store agent (proven pairing).

#define T_SEQ 2048
#define E_DIM 1024
#define H_DIM 1024
#define N3H   3072
#define VTAGS 50
#define VOCAB 50257
#define NWG   64
#define IPW   (H_DIM / NWG)   // 16 h-rows per workgroup
#define SBLK  512

typedef short bf16x8 __attribute__((ext_vector_type(8)));
typedef float f32x4  __attribute__((ext_vector_type(4)));
typedef unsigned int u32x4v __attribute__((ext_vector_type(4)));

__device__ inline unsigned short f2bf_rne(float f) {
  unsigned int u = __float_as_uint(f);
  u += 0x7FFFu + ((u >> 16) & 1u);
  return (unsigned short)(u >> 16);
}

// ---------------- embedding gather + cast to bf16 ----------------
__global__ __launch_bounds__(256) void k_gather_cast(
    const int* __restrict__ sent, const float* __restrict__ emb,
    unsigned short* __restrict__ Xb) {
  const int t = blockIdx.x;
  int row = sent[t];
  row = (row < 0) ? 0 : ((row >= VOCAB) ? VOCAB - 1 : row);
  const float4* src = (const float4*)(emb + (size_t)row * E_DIM);
  float4 v = src[threadIdx.x];
  ushort4 o;
  o.x = f2bf_rne(v.x); o.y = f2bf_rne(v.y); o.z = f2bf_rne(v.z); o.w = f2bf_rne(v.w);
  ((ushort4*)(Xb + (size_t)t * E_DIM))[threadIdx.x] = o;
}

__global__ __launch_bounds__(256) void k_cast_w(
    const float* __restrict__ W, unsigned short* __restrict__ Wb) {
  const int r = blockIdx.x;
  const float4* src = (const float4*)(W + (size_t)r * E_DIM);
  float4 v = src[threadIdx.x];
  ushort4 o;
  o.x = f2bf_rne(v.x); o.y = f2bf_rne(v.y); o.z = f2bf_rne(v.z); o.w = f2bf_rne(v.w);
  ((ushort4*)(Wb + (size_t)r * E_DIM))[threadIdx.x] = o;
}

// ---------------- gi = X @ W_ih^T + b_ih  (bf16 MFMA, fp32 accum) ----------------
__global__ __launch_bounds__(256) void k_gemm_gi(
    const unsigned short* __restrict__ Xb, const unsigned short* __restrict__ Wb,
    const float* __restrict__ b_ih, float* __restrict__ gi) {
  const int tid = threadIdx.x;
  const int lane = tid & 63;
  const int wv = tid >> 6;
  const int m_base = blockIdx.y * 128 + (wv & 1) * 64;
  const int n_base = blockIdx.x * 128 + (wv >> 1) * 64;
  const int lr = lane & 15;
  const int kq = (lane >> 4) * 8;
  f32x4 acc[4][4] = {};
  for (int k0 = 0; k0 < E_DIM; k0 += 32) {
    bf16x8 a[4], b[4];
#pragma unroll
    for (int mi = 0; mi < 4; ++mi)
      a[mi] = *(const bf16x8*)(Xb + (size_t)(m_base + mi * 16 + lr) * E_DIM + k0 + kq);
#pragma unroll
    for (int ni = 0; ni < 4; ++ni)
      b[ni] = *(const bf16x8*)(Wb + (size_t)(n_base + ni * 16 + lr) * E_DIM + k0 + kq);
#pragma unroll
    for (int mi = 0; mi < 4; ++mi)
#pragma unroll
      for (int ni = 0; ni < 4; ++ni)
        acc[mi][ni] = __builtin_amdgcn_mfma_f32_16x16x32_bf16(a[mi], b[ni], acc[mi][ni], 0, 0, 0);
  }
  const int row_q = (lane >> 4) * 4;
#pragma unroll
  for (int mi = 0; mi < 4; ++mi) {
#pragma unroll
    for (int ni = 0; ni < 4; ++ni) {
      const int col  = n_base + ni * 16 + lr;
      const int row0 = m_base + mi * 16 + row_q;
      const float bv = b_ih[col];
#pragma unroll
      for (int rr = 0; rr < 4; ++rr)
        gi[(size_t)(row0 + rr) * N3H + col] = acc[mi][ni][rr] + bv;
    }
  }
}

// ---------------- persistent GRU scan (R4 protocol) ----------------
// 64 WGs x 512 thr, 1 WG/CU (waves_per_eu(2,2): 8 waves x 2/EU cap).
// Thread (row=tid>>5 in 0..15, cg=tid&31): weight cols {4cg+128q+k, q=0..7}
// of rows {i, H+i, 2H+i} = 96 fp32, VGPR-resident.
// Mailbox mb[2][1024] {f32 h, u32 step}, double-buffered by parity.
// Per step: each thread polls its own 2 pairs (dwordx4 sc0 sc1) until tags==t,
// publishes float2 to LDS; barrier (= WG-collective poll-all); FMA+reduce+gates;
// cg==0 agent-stores {h, t+1}. Two-phase safety: a WG stores tag t+1 only after
// ALL its threads read slot t&1, and any WG reaches step t+2 (next overwrite of
// that slot) only after seeing ALL tags t+1 -> overwrite happens-after all reads.
__global__ __launch_bounds__(SBLK) __attribute__((amdgpu_waves_per_eu(2, 2)))
void k_gru_scan(const float* __restrict__ W_hh, const float* __restrict__ b_hh,
                const float* __restrict__ gi, float* __restrict__ hs,
                unsigned long long* mb) {
  const int wg  = blockIdx.x;
  const int tid = threadIdx.x;
  const int row = tid >> 5;        // 0..15 : h-row within WG
  const int cg  = tid & 31;        // 0..31 : column group (interleaved)
  const int i   = wg * IPW + row;  // global h row

  __shared__ float hsh[2][H_DIM];

  // 96 weight floats: cols {4cg + 128q + k} of rows {i, H+i, 2H+i}
  f32x4 w0[8], w1[8], w2[8];
  {
    const f32x4* p0 = (const f32x4*)(W_hh + (size_t)i * H_DIM);
    const f32x4* p1 = (const f32x4*)(W_hh + (size_t)(H_DIM + i) * H_DIM);
    const f32x4* p2 = (const f32x4*)(W_hh + (size_t)(2 * H_DIM + i) * H_DIM);
#pragma unroll
    for (int q = 0; q < 8; ++q) {
      w0[q] = p0[cg + q * 32];
      w1[q] = p1[cg + q * 32];
      w2[q] = p2[cg + q * 32];
      asm volatile("" : "+v"(w0[q]), "+v"(w1[q]), "+v"(w2[q]));
    }
  }
  const float bh0 = b_hh[i], bh1 = b_hh[H_DIM + i], bh2 = b_hh[2 * H_DIM + i];

  for (int t = 0; t < T_SEQ; ++t) {
    // gi prefetch: issued before the poll, completes under it
    const float gir = gi[(size_t)t * N3H + i];
    const float giz = gi[(size_t)t * N3H + H_DIM + i];
    const float gin = gi[(size_t)t * N3H + 2 * H_DIM + i];

    // per-thread poll: 2 pairs (rows 2*tid, 2*tid+1) of slot t&1
    {
      const unsigned long long* pb = mb + (size_t)(t & 1) * H_DIM + tid * 2;
      const unsigned tt = (unsigned)t;
      u32x4v p;
      int it = 0;
      while (true) {
        asm volatile("global_load_dwordx4 %0, %1, off sc0 sc1\n\ts_waitcnt vmcnt(0)"
                     : "=v"(p) : "v"(pb));
        if (__all((p[1] == tt) & (p[3] == tt)) || ++it > (1 << 16)) break;
      }
      *(float2*)&hsh[t & 1][tid * 2] =
          make_float2(__uint_as_float(p[0]), __uint_as_float(p[2]));
    }
    __syncthreads();   // WG-collective poll-all; also orders LDS publish/reads

    const float* hb = hsh[t & 1];
    const f32x4* hb4 = (const f32x4*)hb;
    float a0 = 0.f, a1 = 0.f, a2 = 0.f;
#pragma unroll
    for (int q = 0; q < 8; ++q) {
      f32x4 hv = hb4[cg + q * 32];   // 32 consecutive 16B slots per lane group
      a0 = fmaf(w0[q][0], hv[0], a0); a0 = fmaf(w0[q][1], hv[1], a0);
      a0 = fmaf(w0[q][2], hv[2], a0); a0 = fmaf(w0[q][3], hv[3], a0);
      a1 = fmaf(w1[q][0], hv[0], a1); a1 = fmaf(w1[q][1], hv[1], a1);
      a1 = fmaf(w1[q][2], hv[2], a1); a1 = fmaf(w1[q][3], hv[3], a1);
      a2 = fmaf(w2[q][0], hv[0], a2); a2 = fmaf(w2[q][1], hv[1], a2);
      a2 = fmaf(w2[q][2], hv[2], a2); a2 = fmaf(w2[q][3], hv[3], a2);
    }
#pragma unroll
    for (int off = 16; off >= 1; off >>= 1) {   // reduce across 32-lane group
      a0 += __shfl_xor(a0, off, 64);
      a1 += __shfl_xor(a1, off, 64);
      a2 += __shfl_xor(a2, off, 64);
    }
    const float r = 1.f / (1.f + __expf(-(gir + a0 + bh0)));
    const float z = 1.f / (1.f + __expf(-(giz + a1 + bh1)));
    const float nx = gin + r * (a2 + bh2);
    const float e2 = __expf(-2.f * fabsf(nx));
    float n = (1.f - e2) / (1.f + e2);
    n = (nx < 0.f) ? -n : n;
    const float hold = hb[i];
    const float hnew = (1.f - z) * n + z * hold;

    if (cg == 0) {
      const unsigned long long pack =
          ((unsigned long long)(unsigned)(t + 1) << 32) |
          (unsigned long long)__float_as_uint(hnew);
      __hip_atomic_store(&mb[(size_t)((t + 1) & 1) * H_DIM + i], pack,
                         __ATOMIC_RELAXED, __HIP_MEMORY_SCOPE_AGENT);
      hs[(size_t)t * H_DIM + i] = hnew;   // consumed by k_out after kernel end
    }
    // no bottom barrier needed: mailbox+LDS double-buffered by parity (see header)
  }
}

// ---------------- tag head: hs @ W_out^T + b_out, log_softmax ----------------
__global__ __launch_bounds__(256) void k_out(
    const float* __restrict__ hs, const float* __restrict__ W_out,
    const float* __restrict__ b_out, float* __restrict__ out) {
  const int t = blockIdx.x;
  const int tid = threadIdx.x;
  const int wv = tid >> 6, lane = tid & 63;
  __shared__ float xs[H_DIM];
  __shared__ float tagv[64];
  ((float4*)xs)[tid] = ((const float4*)(hs + (size_t)t * H_DIM))[tid];
  __syncthreads();
  for (int g = wv; g < VTAGS; g += 4) {
    const float4* wr = (const float4*)(W_out + (size_t)g * H_DIM);
    const float4* xr = (const float4*)xs;
    float s = 0.f;
#pragma unroll
    for (int q = 0; q < 4; ++q) {
      float4 a = wr[lane * 4 + q];
      float4 b = xr[lane * 4 + q];
      s += a.x * b.x + a.y * b.y + a.z * b.z + a.w * b.w;
    }
#pragma unroll
    for (int off = 1; off < 64; off <<= 1) s += __shfl_xor(s, off, 64);
    if (lane == 0) tagv[g] = s + b_out[g];
  }
  __syncthreads();
  if (tid < 64) {
    const float v = (tid < VTAGS) ? tagv[tid] : -1e30f;
    float m = v;
#pragma unroll
    for (int off = 1; off < 64; off <<= 1) m = fmaxf(m, __shfl_xor(m, off, 64));
    float e = (tid < VTAGS) ? __expf(v - m) : 0.f;
    float se = e;
#pragma unroll
    for (int off = 1; off < 64; off <<= 1) se += __shfl_xor(se, off, 64);
    const float lse = logf(se);
    if (tid < VTAGS) out[(size_t)t * VTAGS + tid] = v - m - lse;
  }
}

extern "C" void kernel_launch(void* const* d_in, const int* in_sizes, int n_in,
                              void* d_out, int out_size, void* d_ws, size_t ws_size,
                              hipStream_t stream) {
  const int* sent    = (const int*)d_in[0];
  const float* emb   = (const float*)d_in[1];
  const float* W_ih  = (const float*)d_in[2];
  const float* W_hh  = (const float*)d_in[3];
  const float* b_ih  = (const float*)d_in[4];
  const float* b_hh  = (const float*)d_in[5];
  const float* W_out = (const float*)d_in[6];
  const float* b_out = (const float*)d_in[7];
  float* out = (float*)d_out;

  char* ws = (char*)d_ws;
  const size_t OFF_GI = 0;
  const size_t OFF_B  = (size_t)T_SEQ * N3H * 4;            // 24 MB
  const size_t OFF_XB = OFF_B;
  const size_t OFF_WB = OFF_B + (size_t)T_SEQ * E_DIM * 2;  // +4 MB
  const size_t OFF_HS = OFF_B;                              // reuse after GEMM
  const size_t OFF_MB = OFF_B + 10485760;
  const size_t NEED = OFF_MB + 2 * H_DIM * 8;
  if (ws_size < NEED) return;

  float* gi = (float*)(ws + OFF_GI);
  unsigned short* Xb = (unsigned short*)(ws + OFF_XB);
  unsigned short* Wb = (unsigned short*)(ws + OFF_WB);
  float* hs = (float*)(ws + OFF_HS);
  unsigned long long* mb = (unsigned long long*)(ws + OFF_MB);

  // zero mailbox: tags=0 == step 0, h0=0  (re-run on every graph replay)
  hipMemsetAsync(mb, 0, 2 * H_DIM * 8, stream);

  k_gather_cast<<<T_SEQ, 256, 0, stream>>>(sent, emb, Xb);
  k_cast_w<<<N3H, 256, 0, stream>>>(W_ih, Wb);
  k_gemm_gi<<<dim3(N3H / 128, T_SEQ / 128), 256, 0, stream>>>(Xb, Wb, b_ih, gi);
  k_gru_scan<<<NWG, SBLK, 0, stream>>>(W_hh, b_hh, gi, hs, mb);
  k_out<<<T_SEQ, 256, 0, stream>>>(hs, W_out, b_out, out);
}